// Round 5
// baseline (163.236 us; speedup 1.0000x reference)
//
#include <hip/hip_runtime.h>
#include <hip/hip_bf16.h>

typedef __attribute__((ext_vector_type(4))) float f32x4_t;
typedef __attribute__((ext_vector_type(8))) short bf16x8_t;

__device__ __forceinline__ short f2bfs(float x) {
    union { __hip_bfloat16 h; short s; } u;
    u.h = __float2bfloat16(x);   // RNE
    return u.s;
}

// ---------------------------------------------------------------------------
// Kernel 1: build fused 512x512 operator M in fragment-major bf16 layout.
//   c = m*32+o (output col of GEMM), k = n2*32+f (contraction index)
//   M[c][k] = diag[m] * sum_{n,m2} basis[m,n] * Wbig[o,n,f,m2] * basis[n2,m2]
// B-fragment layout for mfma_f32_16x16x32_bf16:
//   flat ushort idx = ((ks*32 + c16)*64 + lane)*8 + j
//   value = M[c16*16 + (lane&15)][ks*32 + (lane>>4)*8 + j]
// ---------------------------------------------------------------------------
__global__ void build_M_kernel(const float* __restrict__ basis,
                               const float* __restrict__ adj,
                               const float* __restrict__ e,
                               const float* __restrict__ We,
                               const float* __restrict__ W2,
                               const float* __restrict__ W3,
                               unsigned short* __restrict__ Mfrag) {
    const int t = blockIdx.x * blockDim.x + threadIdx.x;  // 0..262143
    const int c = t >> 9;           // 0..511
    const int k = t & 511;
    const int m  = c >> 5, o = c & 31;
    const int n2 = k >> 5, f = k & 31;

    float lv[16];
    float mx = -3.4e38f;
#pragma unroll
    for (int j = 0; j < 16; ++j) {
        float a = adj[m * 16 + j];
        float v = (a > 0.0f) ? e[m * 16 + j] : -9.0e15f;
        lv[j] = v;
        mx = fmaxf(mx, v);
    }
    float s = 0.0f;
#pragma unroll
    for (int j = 0; j < 16; ++j) s += expf(lv[j] - mx);
    const float dg = expf(lv[m] - mx) / s;

    float acc = 0.0f;
#pragma unroll
    for (int n = 0; n < 10; ++n) {
        float t2 = 0.0f;
#pragma unroll
        for (int m2 = 0; m2 < 10; ++m2)
            t2 += We[(o * 10 + n) * 320 + f * 10 + m2] * basis[n2 * 16 + m2];
        acc += basis[m * 16 + n] * t2;
    }
#pragma unroll
    for (int n = 0; n < 3; ++n) {
        float t2 = 0.0f;
#pragma unroll
        for (int m2 = 0; m2 < 3; ++m2)
            t2 += W2[(o * 3 + n) * 96 + f * 3 + m2] * basis[n2 * 16 + 10 + m2];
        acc += basis[m * 16 + 10 + n] * t2;
    }
#pragma unroll
    for (int n = 0; n < 3; ++n) {
        float t2 = 0.0f;
#pragma unroll
        for (int m2 = 0; m2 < 3; ++m2)
            t2 += W3[(o * 3 + n) * 96 + f * 3 + m2] * basis[n2 * 16 + 13 + m2];
        acc += basis[m * 16 + 13 + n] * t2;
    }

    const float Mv = dg * acc;

    const int ks = k >> 5;
    const int g  = (k >> 3) & 3;
    const int j  = k & 7;
    const int idx = ((ks * 32 + (c >> 4)) * 64 + ((c & 15) + 16 * g)) * 8 + j;
    Mfrag[idx] = (unsigned short)f2bfs(Mv);
}

// ---------------------------------------------------------------------------
// Kernel 2: Y[131072 x 512] = X[131072 x 512] @ M^T + bias
// Block: 512 threads (8 waves), BM=64 rows, grid 2048.
// K split into 4 quarters (128 K-cols each), each with its OWN 16 KB LDS
// region of bf16 A-fragments (lane-linear, zero-conflict). Per quarter:
//   __syncthreads (region q ready) ; issue quarter q+1 global loads
//   compute(q): 4 ks x { 4 A ds_read_b128, 4 B dwordx4 from L2, 16 MFMA }
//   cvt+ds_write quarter q+1   (consumes the in-flight loads)
// Loads for q+1 are in flight DURING compute(q) -> HBM latency hidden,
// using only __syncthreads() (no raw barriers, no register ping-pong).
// Epilogue: per-wave LDS transpose (stride 68 pad), NT dwordx4 stores.
// ---------------------------------------------------------------------------
__global__ __launch_bounds__(512, 4)
void gemm_kernel(const float* __restrict__ X,
                 const unsigned short* __restrict__ Mfrag,
                 const float* __restrict__ bias,
                 float* __restrict__ Y) {
    __shared__ unsigned short Afrag[4 * 16 * 64 * 8];   // 4 quarter regions, 64 KB

    const int tid  = threadIdx.x;
    const int lane = tid & 63;
    const int wave = tid >> 6;        // 0..7
    const int l15  = lane & 15;
    const int g    = lane >> 4;       // 0..3
    const size_t rowbase = (size_t)blockIdx.x * 64;

    // Staging map per quarter q (1024 entries, 2 per thread: e0=tid, e1=tid+512):
    //   entry e: frag=e>>6 (0..15), lane_e=e&63; ks_in_q=frag>>2, mi=frag&3
    //   value elem j = X[rowbase + mi*16 + (lane_e&15)][q*128 + ks_in_q*32 + (lane_e>>4)*8 + j]
    //   dst = Afrag[q*8192 + frag*512 + lane_e*8]   (ds_write_b128)
    const int f0 = tid >> 6;                 // 0..7
    const int f1 = f0 + 8;                   // 8..15
    const float* src0 = X + (rowbase + (f0 & 3) * 16 + l15) * 512 + (f0 >> 2) * 32 + g * 8;
    const float* src1 = X + (rowbase + (f1 & 3) * 16 + l15) * 512 + (f1 >> 2) * 32 + g * 8;
    unsigned short* dst0 = &Afrag[f0 * 512 + lane * 8];
    unsigned short* dst1 = &Afrag[f1 * 512 + lane * 8];

    const int colbase = wave * 64;
    const unsigned short* bp = Mfrag + ((size_t)((colbase >> 4) * 64) + lane) * 8;

    f32x4_t acc[4][4];
#pragma unroll
    for (int a = 0; a < 4; ++a)
#pragma unroll
        for (int b = 0; b < 4; ++b)
            acc[a][b] = (f32x4_t){0.f, 0.f, 0.f, 0.f};

    auto issue = [&](int q, f32x4_t& A, f32x4_t& B, f32x4_t& C, f32x4_t& D) {
        const float* p0 = src0 + q * 128;
        const float* p1 = src1 + q * 128;
        A = *reinterpret_cast<const f32x4_t*>(p0);
        B = *reinterpret_cast<const f32x4_t*>(p0 + 4);
        C = *reinterpret_cast<const f32x4_t*>(p1);
        D = *reinterpret_cast<const f32x4_t*>(p1 + 4);
    };
    auto cvtwrite = [&](int q, const f32x4_t& A, const f32x4_t& B,
                        const f32x4_t& C, const f32x4_t& D) {
        bf16x8_t v0, v1;
#pragma unroll
        for (int j = 0; j < 4; ++j) {
            v0[j] = f2bfs(A[j]); v0[j + 4] = f2bfs(B[j]);
            v1[j] = f2bfs(C[j]); v1[j + 4] = f2bfs(D[j]);
        }
        *reinterpret_cast<bf16x8_t*>(dst0 + q * 8192) = v0;
        *reinterpret_cast<bf16x8_t*>(dst1 + q * 8192) = v1;
    };
    auto compute = [&](int q) {
#pragma unroll
        for (int ksl = 0; ksl < 4; ++ksl) {
            const int ks = q * 4 + ksl;
            bf16x8_t a[4], b[4];
#pragma unroll
            for (int mi = 0; mi < 4; ++mi)
                a[mi] = *reinterpret_cast<const bf16x8_t*>(&Afrag[(ks * 4 + mi) * 512 + lane * 8]);
#pragma unroll
            for (int ni = 0; ni < 4; ++ni)
                b[ni] = *reinterpret_cast<const bf16x8_t*>(bp + ks * 16384 + ni * 512);
#pragma unroll
            for (int mi = 0; mi < 4; ++mi)
#pragma unroll
                for (int ni = 0; ni < 4; ++ni)
                    acc[mi][ni] = __builtin_amdgcn_mfma_f32_16x16x32_bf16(
                        a[mi], b[ni], acc[mi][ni], 0, 0, 0);
        }
    };

    // ---- pipelined quarters, __syncthreads-only ----
    f32x4_t A0,B0,C0,D0, A1,B1,C1,D1, A2,B2,C2,D2, A3,B3,C3,D3;

    issue(0, A0,B0,C0,D0);
    cvtwrite(0, A0,B0,C0,D0);
    __syncthreads();                 // region 0 ready
    issue(1, A1,B1,C1,D1);           // in flight during compute(0)
    compute(0);
    cvtwrite(1, A1,B1,C1,D1);
    __syncthreads();                 // region 1 ready
    issue(2, A2,B2,C2,D2);
    compute(1);
    cvtwrite(2, A2,B2,C2,D2);
    __syncthreads();                 // region 2 ready
    issue(3, A3,B3,C3,D3);
    compute(2);
    cvtwrite(3, A3,B3,C3,D3);
    __syncthreads();                 // region 3 ready
    compute(3);
    __syncthreads();                 // all reads done; safe to reuse LDS

    // ---- Epilogue: per-wave transpose through LDS (stride 68), NT stores ----
    constexpr int SW = 68;           // padded row stride (floats)
    float* scr = reinterpret_cast<float*>(Afrag) + wave * 2048;  // 8 KB/wave
    const float b_lo = bias[l15];
    const float b_hi = bias[16 + l15];

#pragma unroll
    for (int mi = 0; mi < 4; ++mi) {
#pragma unroll
        for (int ni = 0; ni < 4; ++ni) {
            const float bb = (ni & 1) ? b_hi : b_lo;
#pragma unroll
            for (int r = 0; r < 4; ++r)
                scr[(g * 4 + r) * SW + ni * 16 + l15] = acc[mi][ni][r] + bb;
        }
#pragma unroll
        for (int it = 0; it < 4; ++it) {
            const int flat = it * 64 + lane;   // 0..255
            const int row  = flat >> 4;        // 0..15
            const int c4   = flat & 15;
            f32x4_t v = *reinterpret_cast<const f32x4_t*>(&scr[row * SW + c4 * 4]);
            float* yp = Y + (rowbase + mi * 16 + row) * 512 + colbase + c4 * 4;
            __builtin_nontemporal_store(v, reinterpret_cast<f32x4_t*>(yp));
        }
        __syncthreads();             // order scratch reuse between rounds
    }
}

extern "C" void kernel_launch(void* const* d_in, const int* in_sizes, int n_in,
                              void* d_out, int out_size, void* d_ws, size_t ws_size,
                              hipStream_t stream) {
    const float* x     = (const float*)d_in[0];
    const float* basis = (const float*)d_in[1];
    const float* adj   = (const float*)d_in[2];
    const float* e     = (const float*)d_in[3];
    const float* We    = (const float*)d_in[4];
    const float* W2    = (const float*)d_in[5];
    const float* W3    = (const float*)d_in[6];
    const float* bias  = (const float*)d_in[7];

    unsigned short* Mfrag = (unsigned short*)d_ws;  // 512 KB needed
    if (ws_size < 512u * 512u * 2u) return;

    const int Bsz = in_sizes[0] / 512;              // 131072
    build_M_kernel<<<512, 512, 0, stream>>>(basis, adj, e, We, W2, W3, Mfrag);
    gemm_kernel<<<Bsz / 64, 512, 0, stream>>>(x, Mfrag, bias, (float*)d_out);
}

// Round 6
// 150.597 us; speedup vs baseline: 1.0839x; 1.0839x over previous
//
#include <hip/hip_runtime.h>
#include <hip/hip_bf16.h>

typedef __attribute__((ext_vector_type(4))) float f32x4_t;
typedef __attribute__((ext_vector_type(8))) short bf16x8_t;

__device__ __forceinline__ short f2bfs(float x) {
    union { __hip_bfloat16 h; short s; } u;
    u.h = __float2bfloat16(x);   // RNE
    return u.s;
}

__device__ __forceinline__ void gload_lds16(const float* g, float* l) {
    __builtin_amdgcn_global_load_lds(
        (const __attribute__((address_space(1))) void*)g,
        (__attribute__((address_space(3))) void*)l, 16, 0, 0);
}

// ---------------------------------------------------------------------------
// Kernel 1: build fused 512x512 operator M in fragment-major bf16 layout.
//   c = m*32+o (output col of GEMM), k = n2*32+f (contraction index)
//   M[c][k] = diag[m] * sum_{n,m2} basis[m,n] * Wbig[o,n,f,m2] * basis[n2,m2]
// B-fragment layout for mfma_f32_16x16x32_bf16:
//   flat ushort idx = ((ks*32 + c16)*64 + lane)*8 + j
//   value = M[c16*16 + (lane&15)][ks*32 + (lane>>4)*8 + j]
// ---------------------------------------------------------------------------
__global__ void build_M_kernel(const float* __restrict__ basis,
                               const float* __restrict__ adj,
                               const float* __restrict__ e,
                               const float* __restrict__ We,
                               const float* __restrict__ W2,
                               const float* __restrict__ W3,
                               unsigned short* __restrict__ Mfrag) {
    const int t = blockIdx.x * blockDim.x + threadIdx.x;  // 0..262143
    const int c = t >> 9;           // 0..511
    const int k = t & 511;
    const int m  = c >> 5, o = c & 31;
    const int n2 = k >> 5, f = k & 31;

    float lv[16];
    float mx = -3.4e38f;
#pragma unroll
    for (int j = 0; j < 16; ++j) {
        float a = adj[m * 16 + j];
        float v = (a > 0.0f) ? e[m * 16 + j] : -9.0e15f;
        lv[j] = v;
        mx = fmaxf(mx, v);
    }
    float s = 0.0f;
#pragma unroll
    for (int j = 0; j < 16; ++j) s += expf(lv[j] - mx);
    const float dg = expf(lv[m] - mx) / s;

    float acc = 0.0f;
#pragma unroll
    for (int n = 0; n < 10; ++n) {
        float t2 = 0.0f;
#pragma unroll
        for (int m2 = 0; m2 < 10; ++m2)
            t2 += We[(o * 10 + n) * 320 + f * 10 + m2] * basis[n2 * 16 + m2];
        acc += basis[m * 16 + n] * t2;
    }
#pragma unroll
    for (int n = 0; n < 3; ++n) {
        float t2 = 0.0f;
#pragma unroll
        for (int m2 = 0; m2 < 3; ++m2)
            t2 += W2[(o * 3 + n) * 96 + f * 3 + m2] * basis[n2 * 16 + 10 + m2];
        acc += basis[m * 16 + 10 + n] * t2;
    }
#pragma unroll
    for (int n = 0; n < 3; ++n) {
        float t2 = 0.0f;
#pragma unroll
        for (int m2 = 0; m2 < 3; ++m2)
            t2 += W3[(o * 3 + n) * 96 + f * 3 + m2] * basis[n2 * 16 + 13 + m2];
        acc += basis[m * 16 + 13 + n] * t2;
    }

    const float Mv = dg * acc;

    const int ks = k >> 5;
    const int g  = (k >> 3) & 3;
    const int j  = k & 7;
    const int idx = ((ks * 32 + (c >> 4)) * 64 + ((c & 15) + 16 * g)) * 8 + j;
    Mfrag[idx] = (unsigned short)f2bfs(Mv);
}

// ---------------------------------------------------------------------------
// Kernel 2: Y[131072 x 512] = X[131072 x 512] @ M^T + bias
// Block: 512 threads (8 waves), BM=64 rows, grid 2048 (B L2 traffic 1.05 GB).
// K in 4 quarters of 128; raw f32 quarter (64x128 = 32 KB) double-buffered
// via global_load_lds DMA (compiler can't sink it — no dest regs). Per
// quarter: issue DMA(q+1) -> compute(q) -> __syncthreads (drain overlaps
// compute). XOR-unit swizzle (low 3 bits of 16B-unit ^ row&7), applied as
// inverse on the DMA global source + forward on the ds_read — LDS dest
// stays lane-linear (rule #21). A-fragment b128 reads hit the 8-cycle
// structural floor; cvt f32->bf16 in-loop.
// Epilogue: per-wave private LDS transpose (stride 68, conflict-free
// writes), NT dwordx4 stores, no inter-round barriers.
// ---------------------------------------------------------------------------
__global__ __launch_bounds__(512, 4)
void gemm_kernel(const float* __restrict__ X,
                 const unsigned short* __restrict__ Mfrag,
                 const float* __restrict__ bias,
                 float* __restrict__ Y) {
    __shared__ float lds[16384];      // 64 KB: buf0 = lds[0..8191], buf1 = lds[8192..]

    const int tid  = threadIdx.x;
    const int lane = tid & 63;
    const int wave = tid >> 6;        // 0..7
    const int l15  = lane & 15;
    const int g    = lane >> 4;       // 0..3
    const size_t rowbase = (size_t)blockIdx.x * 64;

    const int colbase = wave * 64;
    const unsigned short* bp = Mfrag + ((size_t)((colbase >> 4) * 64) + lane) * 8;

    f32x4_t acc[4][4];
#pragma unroll
    for (int a = 0; a < 4; ++a)
#pragma unroll
        for (int b = 0; b < 4; ++b)
            acc[a][b] = (f32x4_t){0.f, 0.f, 0.f, 0.f};

    // Stage quarter q (cols q*128..q*128+127, raw f32) into buf b.
    // Per wave: 4 DMA instrs, each 1 KB (2 rows). LDS dest lane-linear:
    // f32 idx = p*256 + lane*4 -> row = 2p + (lane>>5), phys unit = lane&31.
    // Logical unit fetched = phys ^ (row&7)  (involution, low 3 bits).
    auto stage = [&](int q, int b) {
        float* dstbase = &lds[b * 8192];
        const float* xq = X + rowbase * 512 + q * 128;
#pragma unroll
        for (int i = 0; i < 4; ++i) {
            const int p   = wave * 4 + i;          // row-pair 0..31
            const int row = p * 2 + (lane >> 5);
            const int ul  = (lane & 31) ^ (row & 7);
            gload_lds16(xq + (size_t)row * 512 + ul * 4, dstbase + p * 256);
        }
    };

    // Compute quarter q from buf b: 4 ks x { 4 B-frag loads (L2), 4 A-frag
    // reads (2x ds_read_b128 + cvt, swizzled), 16 MFMA }.
    auto compute = [&](int q, int b) {
        const float* buf = &lds[b * 8192];
        const int s = l15 & 7;
#pragma unroll
        for (int ksl = 0; ksl < 4; ++ksl) {
            const int ks = q * 4 + ksl;
            bf16x8_t bfrag[4];
#pragma unroll
            for (int ni = 0; ni < 4; ++ni)
                bfrag[ni] = *reinterpret_cast<const bf16x8_t*>(bp + (size_t)ks * 16384 + ni * 512);
            bf16x8_t afrag[4];
#pragma unroll
            for (int mi = 0; mi < 4; ++mi) {
                const int row  = mi * 16 + l15;
                const int ulo  = (ksl * 8 + g * 2) ^ s;
                const int uhi  = (ksl * 8 + g * 2 + 1) ^ s;
                f32x4_t lo = *reinterpret_cast<const f32x4_t*>(&buf[row * 128 + ulo * 4]);
                f32x4_t hi = *reinterpret_cast<const f32x4_t*>(&buf[row * 128 + uhi * 4]);
#pragma unroll
                for (int j = 0; j < 4; ++j) {
                    afrag[mi][j]     = f2bfs(lo[j]);
                    afrag[mi][j + 4] = f2bfs(hi[j]);
                }
            }
#pragma unroll
            for (int mi = 0; mi < 4; ++mi)
#pragma unroll
                for (int ni = 0; ni < 4; ++ni)
                    acc[mi][ni] = __builtin_amdgcn_mfma_f32_16x16x32_bf16(
                        afrag[mi], bfrag[ni], acc[mi][ni], 0, 0, 0);
        }
    };

    // ---- pipeline: DMA(q+1) in flight during compute(q); __syncthreads
    //      drains it (passively overlapped) and orders buffer reuse ----
    stage(0, 0);
    __syncthreads();
    stage(1, 1);  compute(0, 0);  __syncthreads();
    stage(2, 0);  compute(1, 1);  __syncthreads();
    stage(3, 1);  compute(2, 0);  __syncthreads();
                  compute(3, 1);
    __syncthreads();              // all buf reads done; LDS reusable

    // ---- Epilogue: per-wave private transpose, stride 68, NT stores ----
    constexpr int SW = 68;
    float* scr = &lds[wave * 1088];            // 1088 f32/wave, max idx 8699 < 16384
    const float b_lo = bias[l15];
    const float b_hi = bias[16 + l15];

#pragma unroll
    for (int mi = 0; mi < 4; ++mi) {
#pragma unroll
        for (int ni = 0; ni < 4; ++ni) {
            const float bb = (ni & 1) ? b_hi : b_lo;
#pragma unroll
            for (int r = 0; r < 4; ++r)
                scr[(g * 4 + r) * SW + ni * 16 + l15] = acc[mi][ni][r] + bb;
        }
#pragma unroll
        for (int it = 0; it < 4; ++it) {
            const int flat = it * 64 + lane;   // 0..255
            const int row  = flat >> 4;        // 0..15
            const int c4   = flat & 15;
            f32x4_t v = *reinterpret_cast<const f32x4_t*>(&scr[row * SW + c4 * 4]);
            float* yp = Y + (rowbase + mi * 16 + row) * 512 + colbase + c4 * 4;
            __builtin_nontemporal_store(v, reinterpret_cast<f32x4_t*>(yp));
        }
    }
}

extern "C" void kernel_launch(void* const* d_in, const int* in_sizes, int n_in,
                              void* d_out, int out_size, void* d_ws, size_t ws_size,
                              hipStream_t stream) {
    const float* x     = (const float*)d_in[0];
    const float* basis = (const float*)d_in[1];
    const float* adj   = (const float*)d_in[2];
    const float* e     = (const float*)d_in[3];
    const float* We    = (const float*)d_in[4];
    const float* W2    = (const float*)d_in[5];
    const float* W3    = (const float*)d_in[6];
    const float* bias  = (const float*)d_in[7];

    unsigned short* Mfrag = (unsigned short*)d_ws;  // 512 KB needed
    if (ws_size < 512u * 512u * 2u) return;

    const int Bsz = in_sizes[0] / 512;              // 131072
    build_M_kernel<<<512, 512, 0, stream>>>(basis, adj, e, We, W2, W3, Mfrag);
    gemm_kernel<<<Bsz / 64, 512, 0, stream>>>(x, Mfrag, bias, (float*)d_out);
}